// Round 11
// baseline (34.629 us; speedup 1.0000x reference)
//
#include <hip/hip_runtime.h>

// Post_process_deconv: out = depth + b + sum_k w[k] * (weight[k] - mean_k(weight)) *
//                           bilinear(depth, y - 1 + kh + dy_k, x - 1 + kw + dx_k)
// Shapes: depth [B,1,H,W], weight [B,9,H,W], offset [B,18,H,W], w [1,1,3,3], b [1]
// B=2, H=352, W=1216, K=3, pad=1. All fp32.
//
// Round 11: one block = SAME spatial 64x4 tile in BOTH batches (1672 blocks).
// All 66 VMEM loads (2x6 staging + 2x27 streams) are issued before a SINGLE
// barrier, whose compiler-inserted vmcnt(0) drain is paid once per TWO tiles
// (was once per tile). After the barrier both tile passes are pure reg+LDS
// compute with no VMEM waits. Zero-filled LDS halo keeps zero-outside
// semantics free; rare out-of-halo taps get an exact global fixup.

#define KK 3
#define K2 9
#define PAD 1
#define BB 2
#define HH 352
#define WW 1216

#define TX 64                       // tile width  (19 tiles)
#define TY 4                        // tile height (88 tiles)
#define NTX (WW / TX)               // 19
#define NTY (HH / TY)               // 88
#define NBLK (NTY * NTX)            // 1672 blocks, each does both batches
#define HALO 7
#define SROWS (TY + 2 * HALO + 1)   // 19
#define SCOLS (TX + 2 * HALO + 2)   // 80
#define SN (SROWS * SCOLS)          // 1520
#define NSTG ((SN + 255) / 256)     // 6

__device__ __forceinline__ float tile_compute(
    const float* sdrow, const float* __restrict__ dimg,
    int y, int x, int base_y, int base_x,
    const float* __restrict__ wkp,
    const float* wv, const float* dyv, const float* dxv)
{
    float wsum = 0.f;
#pragma unroll
    for (int k = 0; k < K2; ++k) wsum += wv[k];
    const float wmean = wsum * (1.0f / 9.0f);

    float acc = 0.f;
    unsigned miss = 0u;
#pragma unroll
    for (int k = 0; k < K2; ++k) {
        const int kh = k / KK;
        const int kw = k - kh * KK;
        const float py = (float)(y - PAD + kh) + dyv[k];
        const float px = (float)(x - PAD + kw) + dxv[k];
        const float y0f = floorf(py);
        const float x0f = floorf(px);
        const float fy = py - y0f;
        const float fx = px - x0f;
        const int y0 = (int)y0f;
        const int x0 = (int)x0f;

        const int lr = y0 - base_y;
        const int lc = x0 - base_x;
        const int lrc = min(max(lr, 0), SROWS - 2);
        const int lcc = min(max(lc, 0), SCOLS - 2);
        const bool ok = ((unsigned)lr <= (unsigned)(SROWS - 2)) &
                        ((unsigned)lc <= (unsigned)(SCOLS - 2));

        const float* r0 = &sdrow[lrc * SCOLS + lcc];
        const float v00 = r0[0];
        const float v01 = r0[1];
        const float v10 = r0[SCOLS];
        const float v11 = r0[SCOLS + 1];
        const float s = (1.f - fy) * ((1.f - fx) * v00 + fx * v01)
                      + fy         * ((1.f - fx) * v10 + fx * v11);

        miss |= ok ? 0u : (1u << k);
        acc = fmaf(wkp[k] * (wv[k] - wmean), s, acc);
    }

    // rare exact fixup for taps outside the staged halo (still exact math)
    if (miss) {
#pragma unroll 1
        for (int k = 0; k < K2; ++k) {
            if (!(miss & (1u << k))) continue;
            const int kh = k / KK;
            const int kw = k - kh * KK;
            const float py = (float)(y - PAD + kh) + dyv[k];
            const float px = (float)(x - PAD + kw) + dxv[k];
            const float y0f = floorf(py);
            const float x0f = floorf(px);
            const float fy = py - y0f;
            const float fx = px - x0f;
            const int y0 = (int)y0f;
            const int x0 = (int)x0f;

            // recompute the (wrong) fast-path sample exactly as above
            const int lrc = min(max(y0 - base_y, 0), SROWS - 2);
            const int lcc = min(max(x0 - base_x, 0), SCOLS - 2);
            const float* r0 = &sdrow[lrc * SCOLS + lcc];
            const float sf = (1.f - fy) * ((1.f - fx) * r0[0] + fx * r0[1])
                           + fy         * ((1.f - fx) * r0[SCOLS] + fx * r0[SCOLS + 1]);

            // true sample via global clamped loads + validity-folded weights
            const float wy0 = ((unsigned)y0       < (unsigned)HH) ? (1.f - fy) : 0.f;
            const float wy1 = ((unsigned)(y0 + 1) < (unsigned)HH) ? fy         : 0.f;
            const float wx0 = ((unsigned)x0       < (unsigned)WW) ? (1.f - fx) : 0.f;
            const float wx1 = ((unsigned)(x0 + 1) < (unsigned)WW) ? fx         : 0.f;
            const int y0c = min(max(y0, 0), HH - 1);
            const int y1c = min(max(y0 + 1, 0), HH - 1);
            const int x0c = min(max(x0, 0), WW - 1);
            const int x1c = min(max(x0 + 1, 0), WW - 1);
            const float st = wy0 * (wx0 * dimg[y0c * WW + x0c] + wx1 * dimg[y0c * WW + x1c])
                           + wy1 * (wx0 * dimg[y1c * WW + x0c] + wx1 * dimg[y1c * WW + x1c]);

            acc = fmaf(wkp[k] * (wv[k] - wmean), st - sf, acc);
        }
    }
    return acc;
}

__global__ __launch_bounds__(256, 4) void ppd_kernel(
    const float* __restrict__ depth,   // [B, H*W]
    const float* __restrict__ weight,  // [B, 9, H*W]
    const float* __restrict__ offset,  // [B, 18, H*W]
    const float* __restrict__ wk,      // [9]
    const float* __restrict__ bias,    // [1]
    float* __restrict__ out)           // [B, H*W]
{
    constexpr int HW = HH * WW;

    __shared__ float sd[BB][SN];        // 2 x 6080 B

    const int bid = blockIdx.x;         // 0..1671 — spatial tile id
    const int ty  = bid / NTX;
    const int tx  = bid - ty * NTX;

    const int tid = threadIdx.x;
    const int lx  = tid & (TX - 1);
    const int lyq = tid >> 6;           // 0..3
    const int x   = tx * TX + lx;
    const int y   = ty * TY + lyq;

    const int base_y = ty * TY - HALO;
    const int base_x = tx * TX - HALO;
    const int hw = y * WW + x;

    // ---- Phase 1: staging loads for BOTH batches (zero-filled OOB) ----
    float stg[BB][NSTG];
#pragma unroll
    for (int s = 0; s < BB; ++s) {
        const float* dimg = depth + (size_t)s * HW;
#pragma unroll
        for (int i = 0; i < NSTG; ++i) {
            const int t = tid + i * 256;
            const int r = t / SCOLS;
            const int c = t - r * SCOLS;
            const int gy = base_y + r;
            const int gx = base_x + c;
            float v = 0.f;
            if (t < SN && (unsigned)gy < (unsigned)HH && (unsigned)gx < (unsigned)WW)
                v = dimg[gy * WW + gx];
            stg[s][i] = v;
        }
    }

    // ---- Phase 2: streaming plane loads for BOTH batches (54 loads) ----
    float wv[BB][K2], dyv[BB][K2], dxv[BB][K2];
#pragma unroll
    for (int s = 0; s < BB; ++s) {
        const float* wgt = weight + (size_t)s * (K2 * HW) + hw;
        const float* off = offset + (size_t)s * (2 * K2 * HW) + hw;
#pragma unroll
        for (int k = 0; k < K2; ++k) {
            dyv[s][k] = off[(2 * k)     * HW];
            dxv[s][k] = off[(2 * k + 1) * HW];
        }
#pragma unroll
        for (int k = 0; k < K2; ++k) wv[s][k] = wgt[k * HW];
    }

    // ---- Phase 3: LDS writes for both buffers ----
#pragma unroll
    for (int s = 0; s < BB; ++s) {
#pragma unroll
        for (int i = 0; i < NSTG; ++i) {
            const int t = tid + i * 256;
            if (t < SN) sd[s][t] = stg[s][i];
        }
    }

    // ---- Phase 4: ONE barrier; its vmcnt(0) drain covers all 66 loads ----
    __syncthreads();

    const float bb = bias[0];
    const int ridx = (y - base_y) * SCOLS + (x - base_x);

    // ---- Phase 5: two pure-compute tile passes (regs + LDS only) ----
#pragma unroll
    for (int s = 0; s < BB; ++s) {
        const float* dimg = depth + (size_t)s * HW;
        const float acc = tile_compute(sd[s], dimg, y, x, base_y, base_x,
                                       wk, wv[s], dyv[s], dxv[s]);
        const float dres = sd[s][ridx];
        out[(size_t)s * HW + hw] = acc + bb + dres;
    }
}

extern "C" void kernel_launch(void* const* d_in, const int* in_sizes, int n_in,
                              void* d_out, int out_size, void* d_ws, size_t ws_size,
                              hipStream_t stream) {
    const float* depth  = (const float*)d_in[0];
    const float* weight = (const float*)d_in[1];
    const float* offset = (const float*)d_in[2];
    const float* wk     = (const float*)d_in[3];
    const float* bias   = (const float*)d_in[4];
    float* out = (float*)d_out;

    ppd_kernel<<<NBLK, 256, 0, stream>>>(depth, weight, offset, wk, bias, out);
}

// Round 12
// 25.177 us; speedup vs baseline: 1.3754x; 1.3754x over previous
//
#include <hip/hip_runtime.h>

// Post_process_deconv: out = depth + b + sum_k w[k] * (weight[k] - mean_k(weight)) *
//                           bilinear(depth, y - 1 + kh + dy_k, x - 1 + kw + dx_k)
// Shapes: depth [B,1,H,W], weight [B,9,H,W], offset [B,18,H,W], w [1,1,3,3], b [1]
// B=2, H=352, W=1216, K=3, pad=1. All fp32.
//
// Round 12: round-11's structure (one block = same 64x4 tile in BOTH batches,
// ALL 66 VMEM loads in flight before ONE barrier/drain) redone so registers
// stay registers:
//  - no helper fn (r11's tile_compute pointer args forced wv/dy/dx to scratch:
//    VGPR 52, WRITE_SIZE 63MB of spill traffic);
//  - flat private arrays, compile-time indices only (fully unrolled loops);
//  - rare out-of-halo fixup RELOADS dy/dx/wv from global (avoids runtime
//    array indexing -> scratch), exact math preserved.

#define KK 3
#define K2 9
#define PAD 1
#define BB 2
#define HH 352
#define WW 1216

#define TX 64                       // tile width  (19 tiles)
#define TY 4                        // tile height (88 tiles)
#define NTX (WW / TX)               // 19
#define NTY (HH / TY)               // 88
#define NBLK (NTY * NTX)            // 1672 blocks, each does both batches
#define HALO 7
#define SROWS (TY + 2 * HALO + 1)   // 19
#define SCOLS (TX + 2 * HALO + 2)   // 80
#define SN (SROWS * SCOLS)          // 1520
#define NSTG ((SN + 255) / 256)     // 6

__global__ __launch_bounds__(256, 4) void ppd_kernel(
    const float* __restrict__ depth,   // [B, H*W]
    const float* __restrict__ weight,  // [B, 9, H*W]
    const float* __restrict__ offset,  // [B, 18, H*W]
    const float* __restrict__ wk,      // [9]
    const float* __restrict__ bias,    // [1]
    float* __restrict__ out)           // [B, H*W]
{
    constexpr int HW = HH * WW;

    __shared__ float sd[BB * SN];       // 2 x 6080 B

    const int bid = blockIdx.x;         // 0..1671 — spatial tile id
    const int ty  = bid / NTX;
    const int tx  = bid - ty * NTX;

    const int tid = threadIdx.x;
    const int lx  = tid & (TX - 1);
    const int lyq = tid >> 6;           // 0..3
    const int x   = tx * TX + lx;
    const int y   = ty * TY + lyq;

    const int base_y = ty * TY - HALO;
    const int base_x = tx * TX - HALO;
    const int hw = y * WW + x;

    // ---- Phase 1: staging loads for BOTH batches (12 loads, all in flight) ----
    float stg[BB * NSTG];
#pragma unroll
    for (int s = 0; s < BB; ++s) {
#pragma unroll
        for (int i = 0; i < NSTG; ++i) {
            const int t = tid + i * 256;
            const int r = t / SCOLS;
            const int c = t - r * SCOLS;
            const int gy = base_y + r;
            const int gx = base_x + c;
            float v = 0.f;
            if (t < SN && (unsigned)gy < (unsigned)HH && (unsigned)gx < (unsigned)WW)
                v = depth[(size_t)s * HW + gy * WW + gx];
            stg[s * NSTG + i] = v;
        }
    }

    // ---- Phase 2: streaming plane loads for BOTH batches (54 loads) ----
    float wv[BB * K2], dyv[BB * K2], dxv[BB * K2];
#pragma unroll
    for (int s = 0; s < BB; ++s) {
        const float* wgt = weight + (size_t)s * (K2 * HW) + hw;
        const float* off = offset + (size_t)s * (2 * K2 * HW) + hw;
#pragma unroll
        for (int k = 0; k < K2; ++k) {
            dyv[s * K2 + k] = off[(2 * k)     * HW];
            dxv[s * K2 + k] = off[(2 * k + 1) * HW];
        }
#pragma unroll
        for (int k = 0; k < K2; ++k) wv[s * K2 + k] = wgt[k * HW];
    }

    // ---- Phase 3: LDS writes for both buffers ----
#pragma unroll
    for (int s = 0; s < BB; ++s) {
#pragma unroll
        for (int i = 0; i < NSTG; ++i) {
            const int t = tid + i * 256;
            if (t < SN) sd[s * SN + t] = stg[s * NSTG + i];
        }
    }

    // ---- Phase 4: ONE barrier; its vmcnt(0) drain covers all 66 loads ----
    __syncthreads();

    const float bb  = bias[0];
    const int ridx  = (y - base_y) * SCOLS + (x - base_x);

    // ---- Phase 5: two pure-compute tile passes (regs + LDS only) ----
#pragma unroll
    for (int s = 0; s < BB; ++s) {
        float wsum = 0.f;
#pragma unroll
        for (int k = 0; k < K2; ++k) wsum += wv[s * K2 + k];
        const float wmean = wsum * (1.0f / 9.0f);

        float acc = 0.f;
        unsigned miss = 0u;
#pragma unroll
        for (int k = 0; k < K2; ++k) {
            const int kh = k / KK;
            const int kw = k - kh * KK;
            const float py = (float)(y - PAD + kh) + dyv[s * K2 + k];
            const float px = (float)(x - PAD + kw) + dxv[s * K2 + k];
            const float y0f = floorf(py);
            const float x0f = floorf(px);
            const float fy = py - y0f;
            const float fx = px - x0f;
            const int y0 = (int)y0f;
            const int x0 = (int)x0f;

            const int lr = y0 - base_y;
            const int lc = x0 - base_x;
            const int lrc = min(max(lr, 0), SROWS - 2);
            const int lcc = min(max(lc, 0), SCOLS - 2);
            const bool ok = ((unsigned)lr <= (unsigned)(SROWS - 2)) &
                            ((unsigned)lc <= (unsigned)(SCOLS - 2));

            const float* r0 = &sd[s * SN + lrc * SCOLS + lcc];
            const float v00 = r0[0];
            const float v01 = r0[1];
            const float v10 = r0[SCOLS];
            const float v11 = r0[SCOLS + 1];
            const float smp = (1.f - fy) * ((1.f - fx) * v00 + fx * v01)
                            + fy         * ((1.f - fx) * v10 + fx * v11);

            miss |= ok ? 0u : (1u << k);
            acc = fmaf(wk[k] * (wv[s * K2 + k] - wmean), smp, acc);
        }

        // ---- rare exact fixup: reload per-tap data from GLOBAL (no runtime
        //      indexing of private arrays -> no scratch) ----
        if (miss) {
            const float* dimg = depth  + (size_t)s * HW;
            const float* wgt  = weight + (size_t)s * (K2 * HW) + hw;
            const float* off  = offset + (size_t)s * (2 * K2 * HW) + hw;
#pragma unroll 1
            for (int k = 0; k < K2; ++k) {
                if (!(miss & (1u << k))) continue;
                const int kh = k / KK;
                const int kw = k - kh * KK;
                const float dy = off[(2 * k)     * HW];
                const float dx = off[(2 * k + 1) * HW];
                const float wvk = wgt[k * HW];
                const float py = (float)(y - PAD + kh) + dy;
                const float px = (float)(x - PAD + kw) + dx;
                const float y0f = floorf(py);
                const float x0f = floorf(px);
                const float fy = py - y0f;
                const float fx = px - x0f;
                const int y0 = (int)y0f;
                const int x0 = (int)x0f;

                // recompute the (wrong) fast-path sample exactly as above
                const int lrc = min(max(y0 - base_y, 0), SROWS - 2);
                const int lcc = min(max(x0 - base_x, 0), SCOLS - 2);
                const float* r0 = &sd[s * SN + lrc * SCOLS + lcc];
                const float sf = (1.f - fy) * ((1.f - fx) * r0[0] + fx * r0[1])
                               + fy         * ((1.f - fx) * r0[SCOLS] + fx * r0[SCOLS + 1]);

                // true sample via global clamped loads + validity-folded weights
                const float wy0 = ((unsigned)y0       < (unsigned)HH) ? (1.f - fy) : 0.f;
                const float wy1 = ((unsigned)(y0 + 1) < (unsigned)HH) ? fy         : 0.f;
                const float wx0 = ((unsigned)x0       < (unsigned)WW) ? (1.f - fx) : 0.f;
                const float wx1 = ((unsigned)(x0 + 1) < (unsigned)WW) ? fx         : 0.f;
                const int y0c = min(max(y0, 0), HH - 1);
                const int y1c = min(max(y0 + 1, 0), HH - 1);
                const int x0c = min(max(x0, 0), WW - 1);
                const int x1c = min(max(x0 + 1, 0), WW - 1);
                const float st = wy0 * (wx0 * dimg[y0c * WW + x0c] + wx1 * dimg[y0c * WW + x1c])
                               + wy1 * (wx0 * dimg[y1c * WW + x0c] + wx1 * dimg[y1c * WW + x1c]);

                acc = fmaf(wk[k] * (wvk - wmean), st - sf, acc);
            }
        }

        const float dres = sd[s * SN + ridx];
        out[(size_t)s * HW + hw] = acc + bb + dres;
    }
}

extern "C" void kernel_launch(void* const* d_in, const int* in_sizes, int n_in,
                              void* d_out, int out_size, void* d_ws, size_t ws_size,
                              hipStream_t stream) {
    const float* depth  = (const float*)d_in[0];
    const float* weight = (const float*)d_in[1];
    const float* offset = (const float*)d_in[2];
    const float* wk     = (const float*)d_in[3];
    const float* bias   = (const float*)d_in[4];
    float* out = (float*)d_out;

    ppd_kernel<<<NBLK, 256, 0, stream>>>(depth, weight, offset, wk, bias, out);
}